// Round 6
// baseline (261.299 us; speedup 1.0000x reference)
//
#include <hip/hip_runtime.h>

typedef __bf16 bf16;
typedef __bf16 bf16x4 __attribute__((ext_vector_type(4)));
typedef __bf16 bf16x8 __attribute__((ext_vector_type(8)));
typedef float f32x4 __attribute__((ext_vector_type(4)));

#define TSEQ 2048
#define NHEAD 16

// 0.125 (1/sqrt(Dh)) * log2(e): Q pre-scale so softmax exp becomes exp2
#define QSCALE 0.18033688011112042f

#if __has_builtin(__builtin_amdgcn_exp2f)
#define EXP2F(x) __builtin_amdgcn_exp2f(x)
#else
#define EXP2F(x) exp2f(x)
#endif

// async global->LDS, 16B per lane (lane-linear dest, m97/m104)
__device__ __forceinline__ void gload_lds16(const bf16* g, bf16* s) {
  __builtin_amdgcn_global_load_lds(
      (const __attribute__((address_space(1))) void*)g,
      (__attribute__((address_space(3))) void*)s, 16, 0, 0);
}

// ---------------------------------------------------------------------------
// Fused prep: [0,4096) x fp32->bf16; [4096,7168) w_qkv T+cvt; [7168,8192)
// w_out T+cvt.
// ---------------------------------------------------------------------------
__global__ __launch_bounds__(256) void prep_kernel(
    const float* __restrict__ x, bf16* __restrict__ xbf,
    const float* __restrict__ w_qkv, bf16* __restrict__ wqkvt,
    const float* __restrict__ w_out, bf16* __restrict__ woutt) {
  __shared__ float tile[32][33];
  const int bid = blockIdx.x;
  const int tid = threadIdx.x;
  if (bid < 4096) {
    size_t i = ((size_t)bid * 256 + tid) * 8;
    float4 v0 = ((const float4*)(x + i))[0];
    float4 v1 = ((const float4*)(x + i))[1];
    bf16x8 o;
    o[0] = (bf16)v0.x; o[1] = (bf16)v0.y; o[2] = (bf16)v0.z; o[3] = (bf16)v0.w;
    o[4] = (bf16)v1.x; o[5] = (bf16)v1.y; o[6] = (bf16)v1.z; o[7] = (bf16)v1.w;
    *(bf16x8*)(xbf + i) = o;
    return;
  }
  const float* in; bf16* out; int K, N, n0, k0;
  if (bid < 7168) {
    int q = bid - 4096;
    in = w_qkv; out = wqkvt; K = 1024; N = 3072;
    n0 = (q % 96) * 32; k0 = (q / 96) * 32;
  } else {
    int q = bid - 7168;
    in = w_out; out = woutt; K = 1024; N = 1024;
    n0 = (q & 31) * 32; k0 = (q >> 5) * 32;
  }
  int tx = tid & 31, ty = tid >> 5;
#pragma unroll
  for (int i = ty; i < 32; i += 8)
    tile[i][tx] = in[(size_t)(k0 + i) * N + n0 + tx];
  __syncthreads();
#pragma unroll
  for (int i = ty; i < 32; i += 8)
    out[(size_t)(n0 + i) * K + k0 + tx] = (bf16)tile[tx][i];
}

// ---------------------------------------------------------------------------
// QKV GEMM, 8-phase 256^2 schedule (T3+T4+T5; guide section 5 template).
// C(8192x3072) = Xbf(8192x1024) @ Wqkvt(3072x1024)^T + b_qkv, ldc=2048,
// Q cols [0,1024) scaled by QSCALE, V cols [2048,3072) -> VP transposed.
// BM=BN=256, BK=64, 512 thr = 8 waves (2M x 4N), per-wave C 128x64 with
// INTERLEAVED half mapping: rows = mh*128 + wr*64 + mfp*16, cols =
// nh*128 + wc*32 + nfp*16  =>  phase quadrant (mh,nh) touches exactly one
// A-half / one B-half, making half-tile slot lifetimes disjoint:
//   A-h0 read @ q0,q1 | A-h1 @ q2,q3 | B-h0 @ q0,q2 | B-h1 @ q1,q3.
// Stage schedule (1 half-tile = 2 gloads per phase), provably race-free
// (every gload issued only after the barrier ending its slot's last read):
//   q0: A-h1[kt+1]->dbuf^1   q1: B-h1[kt+1]->dbuf^1
//   q2: A-h0[kt+2]->dbuf     q3: B-h0[kt+2]->dbuf, then vmcnt(4)
// vmcnt(4) once per K-tile guarantees all older half-tiles landed before
// their first read (audited; tail kt=14 needs vmcnt(0) since its issue
// guard breaks the steady-state newest-4 invariant). Raw s_barrier (no
// compiler vmcnt(0) drain), lgkmcnt(0)+sched_barrier before MFMA (rule 18),
// setprio around the 16-MFMA cluster (T5, pays in 8-phase regime).
// k-chunk XOR swizzle identical to the measured-0-conflict 128^2 kernel:
// LDS[row][ch] holds global chunk ch ^ ((row>>1)&7); reader sw=(lm>>1)&7.
// ---------------------------------------------------------------------------
__global__ __launch_bounds__(512, 2) void gemm_qkv_8ph(
    const bf16* __restrict__ A, const bf16* __restrict__ Bt,
    const float* __restrict__ bias, bf16* __restrict__ C,
    bf16* __restrict__ vp) {
  alignas(16) __shared__ bf16 Asl[2][2][128 * 64];
  alignas(16) __shared__ bf16 Bsl[2][2][128 * 64];
  const int row0 = blockIdx.y * 256, col0 = blockIdx.x * 256;
  const int tid = threadIdx.x;
  const int wave = tid >> 6, lane = tid & 63;
  const int quad = lane >> 4, lm = lane & 15;
  const int wr = wave >> 2, wc = wave & 3;
  const int sw = (lm >> 1) & 7;
  const int sr = tid >> 3;                       // 0..63 staging row in slab
  const int js = (tid & 7) ^ ((tid >> 4) & 7);   // pre-swizzled k-chunk
  const bf16* ag = A + (size_t)(row0 + sr) * 1024 + js * 8;
  const bf16* bg = Bt + (size_t)(col0 + sr) * 1024 + js * 8;

#define STA(d, h, s, kt) gload_lds16(ag + (size_t)((h) * 128 + (s) * 64) * 1024 + (kt) * 64, \
                                     &Asl[d][h][(s) * 4096 + tid * 8])
#define STB(d, h, s, kt) gload_lds16(bg + (size_t)((h) * 128 + (s) * 64) * 1024 + (kt) * 64, \
                                     &Bsl[d][h][(s) * 4096 + tid * 8])

  f32x4 acc[8][4];
  const f32x4 z4 = {0.0f, 0.0f, 0.0f, 0.0f};
#pragma unroll
  for (int i = 0; i < 8; i++)
#pragma unroll
    for (int j = 0; j < 4; j++) acc[i][j] = z4;

  // prologue: 6 half-tiles in steady-state stream order; vmcnt(4) -> tile0's
  // 4 half-tiles (oldest 8 loads) landed, A/B-h0[1] may stay in flight.
  STA(0, 0, 0, 0); STA(0, 0, 1, 0);
  STB(0, 0, 0, 0); STB(0, 0, 1, 0);
  STA(0, 1, 0, 0); STA(0, 1, 1, 0);
  STB(0, 1, 0, 0); STB(0, 1, 1, 0);
  STA(1, 0, 0, 1); STA(1, 0, 1, 1);
  STB(1, 0, 0, 1); STB(1, 0, 1, 1);
  asm volatile("s_waitcnt vmcnt(4)" ::: "memory");
  __builtin_amdgcn_s_barrier();
  __builtin_amdgcn_sched_barrier(0);

  for (int kt = 0; kt < 16; ++kt) {
    const int d = kt & 1;
#pragma unroll
    for (int q = 0; q < 4; ++q) {
      const int mh = q >> 1, nh = q & 1;
      // 12 ds_read_b128: 8 A-frags + 4 B-frags for quadrant (mh,nh)
      bf16x8 a8[4][2], b8[2][2];
#pragma unroll
      for (int mfp = 0; mfp < 4; ++mfp)
#pragma unroll
        for (int ks = 0; ks < 2; ++ks)
          a8[mfp][ks] = *(const bf16x8*)&Asl[d][mh][(wr * 64 + mfp * 16 + lm) * 64 +
                                                    ((ks * 4 + quad) ^ sw) * 8];
#pragma unroll
      for (int nfp = 0; nfp < 2; ++nfp)
#pragma unroll
        for (int ks = 0; ks < 2; ++ks)
          b8[nfp][ks] = *(const bf16x8*)&Bsl[d][nh][(wc * 32 + nfp * 16 + lm) * 64 +
                                                    ((ks * 4 + quad) ^ sw) * 8];
      // stage one half-tile (slot's last reader phase already barriered off)
      if (q == 0 && kt + 1 < 16) { STA(d ^ 1, 1, 0, kt + 1); STA(d ^ 1, 1, 1, kt + 1); }
      if (q == 1 && kt + 1 < 16) { STB(d ^ 1, 1, 0, kt + 1); STB(d ^ 1, 1, 1, kt + 1); }
      if (q == 2 && kt + 2 < 16) { STA(d, 0, 0, kt + 2); STA(d, 0, 1, kt + 2); }
      if (q == 3 && kt + 2 < 16) { STB(d, 0, 0, kt + 2); STB(d, 0, 1, kt + 2); }
      __builtin_amdgcn_s_barrier();
      asm volatile("s_waitcnt lgkmcnt(0)" ::: "memory");
      __builtin_amdgcn_sched_barrier(0);
      __builtin_amdgcn_s_setprio(1);
#pragma unroll
      for (int mfp = 0; mfp < 4; ++mfp)
#pragma unroll
        for (int nfp = 0; nfp < 2; ++nfp)
#pragma unroll
          for (int ks = 0; ks < 2; ++ks)
            acc[mh * 4 + mfp][nh * 2 + nfp] = __builtin_amdgcn_mfma_f32_16x16x32_bf16(
                a8[mfp][ks], b8[nfp][ks], acc[mh * 4 + mfp][nh * 2 + nfp], 0, 0, 0);
      __builtin_amdgcn_s_setprio(0);
      if (q == 3) {
        if (kt < 14)
          asm volatile("s_waitcnt vmcnt(4)" ::: "memory");
        else
          asm volatile("s_waitcnt vmcnt(0)" ::: "memory");
      }
      __builtin_amdgcn_s_barrier();
      __builtin_amdgcn_sched_barrier(0);
    }
  }

  // epilogue
#pragma unroll
  for (int nf = 0; nf < 4; ++nf) {
    const int gc = col0 + (nf >> 1) * 128 + wc * 32 + (nf & 1) * 16 + lm;
    const float bb = bias[gc];
    if (gc >= 2048) {
      // V part -> VP transposed [(b*1024 + gc-2048)][t]
      const size_t vbase = (size_t)(gc - 2048) * TSEQ;
#pragma unroll
      for (int mf = 0; mf < 8; ++mf) {
        const int gr0 = row0 + (mf >> 2) * 128 + wr * 64 + (mf & 3) * 16 + quad * 4;
        const int b = gr0 >> 11;
        const size_t vrow = (size_t)b * 1024 * TSEQ + vbase;
        const int t = gr0 & (TSEQ - 1);
        bf16x4 vk;
#pragma unroll
        for (int rr = 0; rr < 4; ++rr) vk[rr] = (bf16)(acc[mf][nf][rr] + bb);
        *(bf16x4*)(vp + vrow + t) = vk;
      }
    } else {
      const float sc2 = (gc < 1024) ? QSCALE : 1.0f;
#pragma unroll
      for (int mf = 0; mf < 8; ++mf) {
        const int gr0 = row0 + (mf >> 2) * 128 + wr * 64 + (mf & 3) * 16 + quad * 4;
#pragma unroll
        for (int rr = 0; rr < 4; ++rr)
          C[(size_t)(gr0 + rr) * 2048 + gc] = (bf16)((acc[mf][nf][rr] + bb) * sc2);
      }
    }
  }
#undef STA
#undef STB
}

// ---------------------------------------------------------------------------
// GEMM (m97-structure 128xBN): used for the out-projection only.
// SWZ (T1 m204 bijective XCD-chunk): on for out-GEMM (A-slab 2MB + B 2MB
// both fit per-XCD L2). See R4/R5 notes: chunking hurt QKV (B 6.3MB).
// ---------------------------------------------------------------------------
template <typename OutT, int BN, bool SWZ>
__global__ __launch_bounds__(256, 4) void gemm_bf16_kernel(
    const bf16* __restrict__ A, const bf16* __restrict__ Bt,
    const float* __restrict__ bias, OutT* __restrict__ C,
    int M, int N, int K, int ldc, float scale0, int scale_cols,
    bf16* __restrict__ vp) {
  constexpr int BG = BN / 32;           // B chunk groups (4 or 2)
  constexpr int JN = BN / 32;           // per-wave N-frags (4 or 2)
  alignas(16) __shared__ bf16 As[128 * 64];
  alignas(16) __shared__ bf16 Bs[BN * 64];

  int bx, by;
  if (SWZ) {
    const int nwg = gridDim.x * gridDim.y;
    const int orig = blockIdx.y * gridDim.x + blockIdx.x;
    const int xcd = orig & 7, qch = nwg >> 3;
    const int wgid = xcd * qch + (orig >> 3);
    bx = wgid % gridDim.x; by = wgid / gridDim.x;
  } else {
    bx = blockIdx.x; by = blockIdx.y;
  }

  const int row0 = by * 128, col0 = bx * BN;
  const int tid = threadIdx.x;
  const int wave = tid >> 6, lane = tid & 63;
  const int quad = lane >> 4, lm = lane & 15;
  const int wm = (wave >> 1) * 64, wn = (wave & 1) * (BN / 2);

  f32x4 acc[4][JN];
  const f32x4 z4 = {0.0f, 0.0f, 0.0f, 0.0f};
#pragma unroll
  for (int i = 0; i < 4; i++)
#pragma unroll
    for (int j = 0; j < JN; j++) acc[i][j] = z4;

  const int sr0 = tid >> 3;
  const int js = (tid & 7) ^ ((tid >> 4) & 7);
  const bf16* apg = A + (size_t)(row0 + sr0) * K + js * 8;
  const bf16* bpg = Bt + (size_t)(col0 + sr0) * K + js * 8;
  const size_t row32 = (size_t)32 * K;

  const int sw = (lm >> 1) & 7;

  for (int k0 = 0; k0 < K; k0 += 64) {
    __syncthreads();
#pragma unroll
    for (int p = 0; p < 4; p++)
      gload_lds16(apg + p * row32, &As[(p * 256 + tid) * 8]);
#pragma unroll
    for (int p = 0; p < BG; p++)
      gload_lds16(bpg + p * row32, &Bs[(p * 256 + tid) * 8]);
    apg += 64; bpg += 64;
    __syncthreads();

#pragma unroll
    for (int ks = 0; ks < 2; ks++) {
      const int kc = ((ks * 4 + quad) ^ sw) * 8;
      bf16x8 af[4], bfr[JN];
#pragma unroll
      for (int i = 0; i < 4; i++)
        af[i] = *(const bf16x8*)&As[(wm + i * 16 + lm) * 64 + kc];
#pragma unroll
      for (int j = 0; j < JN; j++)
        bfr[j] = *(const bf16x8*)&Bs[(wn + j * 16 + lm) * 64 + kc];
#pragma unroll
      for (int i = 0; i < 4; i++)
#pragma unroll
        for (int j = 0; j < JN; j++)
          acc[i][j] = __builtin_amdgcn_mfma_f32_16x16x32_bf16(af[i], bfr[j], acc[i][j], 0, 0, 0);
    }
  }

#pragma unroll
  for (int j = 0; j < JN; j++) {
    int gc = col0 + wn + j * 16 + lm;
    float bb = bias[gc];
    float sc2 = (gc < scale_cols) ? scale0 : 1.0f;
    if (vp != nullptr && gc >= 2048) {
      int gr0 = row0 + wm + quad * 4;
      int b = gr0 >> 11;
      size_t vrow = (size_t)(b * 1024 + gc - 2048) * TSEQ;
#pragma unroll
      for (int i = 0; i < 4; i++) {
        int t = (gr0 + i * 16) & (TSEQ - 1);
        bf16x4 vk;
#pragma unroll
        for (int rr = 0; rr < 4; rr++) vk[rr] = (bf16)(acc[i][j][rr] + bb);
        *(bf16x4*)(vp + vrow + t) = vk;
      }
    } else {
#pragma unroll
      for (int i = 0; i < 4; i++) {
        int gr = row0 + wm + i * 16 + quad * 4;
#pragma unroll
        for (int rr = 0; rr < 4; rr++) {
          float v = (acc[i][j][rr] + bb) * sc2;
          C[(size_t)(gr + rr) * ldc + gc] = (OutT)v;
        }
      }
    }
  }
}

// ---------------------------------------------------------------------------
// Flash attention (R0 structure): cooperative LDS staging of K/V
// (global_load_lds, XOR-swizzled 64-stride tiles, conflict-free). Fixed-shift
// softmax via exp2 (Q pre-scaled by 0.125*log2e in the QKV GEMM). S^T/O^T
// forms, per-lane l partials reduced once per q-tile. qk buffer: rows
// (b*T+t), stride 2048, Q cols [0,1024), K cols [1024,2048). LDS 32KB,
// 4 blk/CU. qt map {15-r,r,11-r,4+r}: co-resident blocks per CU sum to 68
// k-tiles. hb in blockIdx.x keeps each (h,b) on one XCD (K/V L2 reuse).
// ---------------------------------------------------------------------------
__global__ __launch_bounds__(256, 4) void flash_attn_kernel(
    const bf16* __restrict__ qk, const bf16* __restrict__ vp,
    bf16* __restrict__ att) {
  alignas(16) __shared__ bf16 Ks[64 * 64];
  alignas(16) __shared__ bf16 Vts[64 * 64];
  alignas(16) __shared__ bf16 Ps[4][32 * 64];

  const int hb = blockIdx.x;
  const int h = hb & 15, b = hb >> 4;
  const int y = blockIdx.y;
  const int g = y >> 2, r = y & 3;
  const int qt = (g == 0) ? (15 - r) : (g == 1) ? r : (g == 2) ? (11 - r) : (4 + r);
  const int q0 = qt * 128;
  const int tid = threadIdx.x;
  const int wave = tid >> 6, lane = tid & 63;
  const int quad = lane >> 4, lm = lane & 15;
  const size_t rowbase = (size_t)b * TSEQ;
  const f32x4 z4 = {0.0f, 0.0f, 0.0f, 0.0f};

  // Q fragments (B-operand), direct from global (pre-scaled by 0.125*log2e)
  bf16x8 bq[2][2];
#pragma unroll
  for (int nf = 0; nf < 2; nf++)
#pragma unroll
    for (int ks = 0; ks < 2; ks++)
      bq[nf][ks] = *(const bf16x8*)(qk +
          (rowbase + q0 + wave * 32 + nf * 16 + lm) * 2048 + h * 64 + ks * 32 + quad * 8);

  const int strow = tid >> 3;
  const int js = (tid & 7) ^ ((tid >> 4) & 7);
  const bf16* kstg = qk + (rowbase + strow) * 2048 + 1024 + h * 64 + js * 8;
  const bf16* vstg = vp + ((size_t)hb * 64 + strow) * TSEQ + js * 8;
  const size_t krow32 = (size_t)32 * 2048;
  const size_t vrow32 = (size_t)32 * TSEQ;

  const int sw = (lm >> 1) & 7;

  f32x4 oT[4][2];
#pragma unroll
  for (int mf = 0; mf < 4; mf++)
#pragma unroll
    for (int nf = 0; nf < 2; nf++) oT[mf][nf] = z4;
  float lp[2] = {0.0f, 0.0f};

  const int nkt = 2 * qt + 2;
  const int wrow_lo = q0 + wave * 32;
  const int wrow_hi = wrow_lo + 31;

  for (int kt = 0; kt < nkt; kt++) {
    const int k0 = kt * 64;
    __syncthreads();
    gload_lds16(kstg + (size_t)k0 * 2048, &Ks[tid * 8]);
    gload_lds16(kstg + (size_t)k0 * 2048 + krow32, &Ks[(256 + tid) * 8]);
    gload_lds16(vstg + k0, &Vts[tid * 8]);
    gload_lds16(vstg + k0 + vrow32, &Vts[(256 + tid) * 8]);
    __syncthreads();
    if (k0 > wrow_hi) continue;  // wave fully above diagonal (still barriers)

    // ---- S^T = K Q^T ----
    f32x4 s[4][2];
#pragma unroll
    for (int mf = 0; mf < 4; mf++)
#pragma unroll
      for (int nf = 0; nf < 2; nf++) s[mf][nf] = z4;
#pragma unroll
    for (int ks = 0; ks < 2; ks++) {
      const int kc = ((ks * 4 + quad) ^ sw) * 8;
      bf16x8 ak[4];
#pragma unroll
      for (int mf = 0; mf < 4; mf++)
        ak[mf] = *(const bf16x8*)&Ks[(mf * 16 + lm) * 64 + kc];
#pragma unroll
      for (int mf = 0; mf < 4; mf++)
#pragma unroll
        for (int nf = 0; nf < 2; nf++)
          s[mf][nf] = __builtin_amdgcn_mfma_f32_16x16x32_bf16(ak[mf], bq[nf][ks], s[mf][nf], 0, 0, 0);
    }

    // ---- P = exp2(S^T) (log2e pre-folded); mask only on diagonal tiles ----
    const bool need_mask = (k0 + 63 > wrow_lo);
#pragma unroll
    for (int nf = 0; nf < 2; nf++) {
      const int qrow = q0 + wave * 32 + nf * 16 + lm;
#pragma unroll
      for (int mf = 0; mf < 4; mf++) {
        bf16x4 pk;
        float psum = 0.0f;
#pragma unroll
        for (int rr = 0; rr < 4; rr++) {
          float pv = EXP2F(s[mf][nf][rr]);
          if (need_mask) {
            int kv = k0 + mf * 16 + quad * 4 + rr;
            pv = (kv > qrow) ? 0.0f : pv;
          }
          psum += pv;
          pk[rr] = (bf16)pv;
        }
        lp[nf] += psum;
        *(bf16x4*)&Ps[wave][(nf * 16 + lm) * 64 +
                            (((mf * 2 + (quad >> 1)) ^ sw) * 8 + (quad & 1) * 4)] = pk;
      }
    }

    // ---- O^T += V^T P^T ----
#pragma unroll
    for (int ks = 0; ks < 2; ks++) {
      const int kc = ((ks * 4 + quad) ^ sw) * 8;
      bf16x8 av[4], bp[2];
#pragma unroll
      for (int mf = 0; mf < 4; mf++)
        av[mf] = *(const bf16x8*)&Vts[(mf * 16 + lm) * 64 + kc];
#pragma unroll
      for (int nf = 0; nf < 2; nf++)
        bp[nf] = *(const bf16x8*)&Ps[wave][(nf * 16 + lm) * 64 + kc];
#pragma unroll
      for (int mf = 0; mf < 4; mf++)
#pragma unroll
        for (int nf = 0; nf < 2; nf++)
          oT[mf][nf] = __builtin_amdgcn_mfma_f32_16x16x32_bf16(av[mf], bp[nf], oT[mf][nf], 0, 0, 0);
    }
  }

  float linv[2];
#pragma unroll
  for (int nf = 0; nf < 2; nf++) {
    float l = lp[nf];
    l += __shfl_xor(l, 16, 64);
    l += __shfl_xor(l, 32, 64);
    linv[nf] = 1.0f / l;
  }

#pragma unroll
  for (int nf = 0; nf < 2; nf++) {
    const size_t grow = rowbase + q0 + wave * 32 + nf * 16 + lm;
#pragma unroll
    for (int mf = 0; mf < 4; mf++) {
      bf16x4 ok;
#pragma unroll
      for (int rr = 0; rr < 4; rr++) ok[rr] = (bf16)(oT[mf][nf][rr] * linv[nf]);
      *(bf16x4*)(att + grow * 1024 + h * 64 + mf * 16 + quad * 4) = ok;
    }
  }
}

extern "C" void kernel_launch(void* const* d_in, const int* in_sizes, int n_in,
                              void* d_out, int out_size, void* d_ws, size_t ws_size,
                              hipStream_t stream) {
  const float* x = (const float*)d_in[0];
  const float* w_qkv = (const float*)d_in[1];
  const float* b_qkv = (const float*)d_in[2];
  const float* w_out = (const float*)d_in[3];
  const float* b_out = (const float*)d_in[4];
  float* out = (float*)d_out;

  // Workspace (75.5 MB). ATT aliases Xbf: Xbf is dead once the QKV GEMM has
  // run; flash writes ATT strictly after that on the same stream.
  char* ws = (char*)d_ws;
  bf16* Xbf   = (bf16*)(ws);                 // 8192x1024  (16.78 MB)
  bf16* ATT   = (bf16*)(ws);                 // aliases Xbf
  bf16* Wqkvt = (bf16*)(ws + 16777216);      // 3072x1024  ( 6.29 MB)
  bf16* Woutt = (bf16*)(ws + 23068672);      // 1024x1024  ( 2.10 MB)
  bf16* QK    = (bf16*)(ws + 25165824);      // 8192x2048  (33.55 MB) Q|K
  bf16* VP    = (bf16*)(ws + 58720256);      // [b*1024+h*64+d][t] (16.78 MB)

  prep_kernel<<<8192, 256, 0, stream>>>(x, Xbf, w_qkv, Wqkvt, w_out, Woutt);
  // QKV GEMM: 8-phase 256^2 (natural raster; grid 12x32 = 384 blocks)
  gemm_qkv_8ph<<<dim3(12, 32), 512, 0, stream>>>(Xbf, Wqkvt, b_qkv, QK, VP);
  flash_attn_kernel<<<dim3(64, 16, 1), 256, 0, stream>>>(QK, VP, ATT);
  // out GEMM: T1 chunk swizzle (A-slab 2MB + B 2MB both L2-resident)
  gemm_bf16_kernel<float, 64, true><<<dim3(16, 64), 256, 0, stream>>>(
      ATT, Woutt, b_out, out, 8192, 1024, 1024, 1024, 1.0f, 0, nullptr);
}

// Round 7
// 226.177 us; speedup vs baseline: 1.1553x; 1.1553x over previous
//
#include <hip/hip_runtime.h>

typedef __bf16 bf16;
typedef __bf16 bf16x4 __attribute__((ext_vector_type(4)));
typedef __bf16 bf16x8 __attribute__((ext_vector_type(8)));
typedef float f32x4 __attribute__((ext_vector_type(4)));

#define TSEQ 2048
#define NHEAD 16

// 0.125 (1/sqrt(Dh)) * log2(e): Q pre-scale so softmax exp becomes exp2
#define QSCALE 0.18033688011112042f

#if __has_builtin(__builtin_amdgcn_exp2f)
#define EXP2F(x) __builtin_amdgcn_exp2f(x)
#else
#define EXP2F(x) exp2f(x)
#endif

// async global->LDS, 16B per lane (lane-linear dest, m97/m104)
__device__ __forceinline__ void gload_lds16(const bf16* g, bf16* s) {
  __builtin_amdgcn_global_load_lds(
      (const __attribute__((address_space(1))) void*)g,
      (__attribute__((address_space(3))) void*)s, 16, 0, 0);
}

// ---------------------------------------------------------------------------
// Fused prep: [0,4096) x fp32->bf16; [4096,7168) w_qkv T+cvt; [7168,8192)
// w_out T+cvt.
// ---------------------------------------------------------------------------
__global__ __launch_bounds__(256) void prep_kernel(
    const float* __restrict__ x, bf16* __restrict__ xbf,
    const float* __restrict__ w_qkv, bf16* __restrict__ wqkvt,
    const float* __restrict__ w_out, bf16* __restrict__ woutt) {
  __shared__ float tile[32][33];
  const int bid = blockIdx.x;
  const int tid = threadIdx.x;
  if (bid < 4096) {
    size_t i = ((size_t)bid * 256 + tid) * 8;
    float4 v0 = ((const float4*)(x + i))[0];
    float4 v1 = ((const float4*)(x + i))[1];
    bf16x8 o;
    o[0] = (bf16)v0.x; o[1] = (bf16)v0.y; o[2] = (bf16)v0.z; o[3] = (bf16)v0.w;
    o[4] = (bf16)v1.x; o[5] = (bf16)v1.y; o[6] = (bf16)v1.z; o[7] = (bf16)v1.w;
    *(bf16x8*)(xbf + i) = o;
    return;
  }
  const float* in; bf16* out; int K, N, n0, k0;
  if (bid < 7168) {
    int q = bid - 4096;
    in = w_qkv; out = wqkvt; K = 1024; N = 3072;
    n0 = (q % 96) * 32; k0 = (q / 96) * 32;
  } else {
    int q = bid - 7168;
    in = w_out; out = woutt; K = 1024; N = 1024;
    n0 = (q & 31) * 32; k0 = (q >> 5) * 32;
  }
  int tx = tid & 31, ty = tid >> 5;
#pragma unroll
  for (int i = ty; i < 32; i += 8)
    tile[i][tx] = in[(size_t)(k0 + i) * N + n0 + tx];
  __syncthreads();
#pragma unroll
  for (int i = ty; i < 32; i += 8)
    out[(size_t)(n0 + i) * K + k0 + tx] = (bf16)tile[tx][i];
}

// ---------------------------------------------------------------------------
// GEMM (m97-structure 128xBN): C(MxN) = A(MxK) @ Bt(NxK)^T + bias.
// BK=64, global_load_lds width-16 staging, XOR-swizzled k-chunks (0
// conflicts measured). Columns gc < scale_cols get *scale0. C row stride =
// ldc; if vp != null, columns gc >= 2048 (V of QKV) go transposed to
// vp[(b*1024+gc-2048)*2048+t], not written to C.
//
// LEDGER: R6 8-phase 256^2 port = 101us vs this structure's 61.8 (1 blk/CU
// at 128KB LDS, 1.5-round grid tail, coarse phase-split) -> reverted; this
// is the m97 ceiling (~834 TF here) and stays.
// SWZ (T1 m204 bijective XCD-chunk): only when per-XCD chunk operands fit
// L2 (4MiB). R4 measured: out-GEMM fits (+~18us); QKV's B=6.3MB does not
// (B re-stream, 62->77.5us) -> QKV natural raster.
// ---------------------------------------------------------------------------
template <typename OutT, int BN, bool SWZ>
__global__ __launch_bounds__(256, 4) void gemm_bf16_kernel(
    const bf16* __restrict__ A, const bf16* __restrict__ Bt,
    const float* __restrict__ bias, OutT* __restrict__ C,
    int M, int N, int K, int ldc, float scale0, int scale_cols,
    bf16* __restrict__ vp) {
  constexpr int BG = BN / 32;           // B chunk groups (4 or 2)
  constexpr int JN = BN / 32;           // per-wave N-frags (4 or 2)
  alignas(16) __shared__ bf16 As[128 * 64];
  alignas(16) __shared__ bf16 Bs[BN * 64];

  int bx, by;
  if (SWZ) {
    const int nwg = gridDim.x * gridDim.y;
    const int orig = blockIdx.y * gridDim.x + blockIdx.x;
    const int xcd = orig & 7, qch = nwg >> 3;
    const int wgid = xcd * qch + (orig >> 3);
    bx = wgid % gridDim.x; by = wgid / gridDim.x;
  } else {
    bx = blockIdx.x; by = blockIdx.y;
  }

  const int row0 = by * 128, col0 = bx * BN;
  const int tid = threadIdx.x;
  const int wave = tid >> 6, lane = tid & 63;
  const int quad = lane >> 4, lm = lane & 15;
  const int wm = (wave >> 1) * 64, wn = (wave & 1) * (BN / 2);

  f32x4 acc[4][JN];
  const f32x4 z4 = {0.0f, 0.0f, 0.0f, 0.0f};
#pragma unroll
  for (int i = 0; i < 4; i++)
#pragma unroll
    for (int j = 0; j < JN; j++) acc[i][j] = z4;

  const int sr0 = tid >> 3;
  const int js = (tid & 7) ^ ((tid >> 4) & 7);
  const bf16* apg = A + (size_t)(row0 + sr0) * K + js * 8;
  const bf16* bpg = Bt + (size_t)(col0 + sr0) * K + js * 8;
  const size_t row32 = (size_t)32 * K;

  const int sw = (lm >> 1) & 7;

  for (int k0 = 0; k0 < K; k0 += 64) {
    __syncthreads();
#pragma unroll
    for (int p = 0; p < 4; p++)
      gload_lds16(apg + p * row32, &As[(p * 256 + tid) * 8]);
#pragma unroll
    for (int p = 0; p < BG; p++)
      gload_lds16(bpg + p * row32, &Bs[(p * 256 + tid) * 8]);
    apg += 64; bpg += 64;
    __syncthreads();

#pragma unroll
    for (int ks = 0; ks < 2; ks++) {
      const int kc = ((ks * 4 + quad) ^ sw) * 8;
      bf16x8 af[4], bfr[JN];
#pragma unroll
      for (int i = 0; i < 4; i++)
        af[i] = *(const bf16x8*)&As[(wm + i * 16 + lm) * 64 + kc];
#pragma unroll
      for (int j = 0; j < JN; j++)
        bfr[j] = *(const bf16x8*)&Bs[(wn + j * 16 + lm) * 64 + kc];
#pragma unroll
      for (int i = 0; i < 4; i++)
#pragma unroll
        for (int j = 0; j < JN; j++)
          acc[i][j] = __builtin_amdgcn_mfma_f32_16x16x32_bf16(af[i], bfr[j], acc[i][j], 0, 0, 0);
    }
  }

#pragma unroll
  for (int j = 0; j < JN; j++) {
    int gc = col0 + wn + j * 16 + lm;
    float bb = bias[gc];
    float sc2 = (gc < scale_cols) ? scale0 : 1.0f;
    if (vp != nullptr && gc >= 2048) {
      int gr0 = row0 + wm + quad * 4;
      int b = gr0 >> 11;
      size_t vrow = (size_t)(b * 1024 + gc - 2048) * TSEQ;
#pragma unroll
      for (int i = 0; i < 4; i++) {
        int t = (gr0 + i * 16) & (TSEQ - 1);
        bf16x4 vk;
#pragma unroll
        for (int rr = 0; rr < 4; rr++) vk[rr] = (bf16)(acc[i][j][rr] + bb);
        *(bf16x4*)(vp + vrow + t) = vk;
      }
    } else {
#pragma unroll
      for (int i = 0; i < 4; i++) {
        int gr = row0 + wm + i * 16 + quad * 4;
#pragma unroll
        for (int rr = 0; rr < 4; rr++) {
          float v = (acc[i][j][rr] + bb) * sc2;
          C[(size_t)(gr + rr) * ldc + gc] = (OutT)v;
        }
      }
    }
  }
}

// ---------------------------------------------------------------------------
// Flash attention (R0 structure): cooperative LDS staging of K/V
// (global_load_lds, XOR-swizzled 64-stride tiles, conflict-free). Fixed-shift
// softmax via exp2 (Q pre-scaled by 0.125*log2e in the QKV GEMM). S^T/O^T
// forms, per-lane l partials reduced once per q-tile. qk buffer: rows
// (b*T+t), stride 2048, Q cols [0,1024), K cols [1024,2048). LDS 32KB,
// 4 blk/CU. qt map {15-r,r,11-r,4+r}: co-resident blocks per CU sum to 68
// k-tiles. hb in blockIdx.x keeps each (h,b) on one XCD (K/V L2 reuse).
// LEDGER: dbuf (R1, -3us: LDS occupancy), split-K (R2, 0), no-LDS direct
// loads (R3, -82us: exposed latency) -> this structure stands at 61.4-61.7.
// ---------------------------------------------------------------------------
__global__ __launch_bounds__(256, 4) void flash_attn_kernel(
    const bf16* __restrict__ qk, const bf16* __restrict__ vp,
    bf16* __restrict__ att) {
  alignas(16) __shared__ bf16 Ks[64 * 64];
  alignas(16) __shared__ bf16 Vts[64 * 64];
  alignas(16) __shared__ bf16 Ps[4][32 * 64];

  const int hb = blockIdx.x;
  const int h = hb & 15, b = hb >> 4;
  const int y = blockIdx.y;
  const int g = y >> 2, r = y & 3;
  const int qt = (g == 0) ? (15 - r) : (g == 1) ? r : (g == 2) ? (11 - r) : (4 + r);
  const int q0 = qt * 128;
  const int tid = threadIdx.x;
  const int wave = tid >> 6, lane = tid & 63;
  const int quad = lane >> 4, lm = lane & 15;
  const size_t rowbase = (size_t)b * TSEQ;
  const f32x4 z4 = {0.0f, 0.0f, 0.0f, 0.0f};

  // Q fragments (B-operand), direct from global (pre-scaled by 0.125*log2e)
  bf16x8 bq[2][2];
#pragma unroll
  for (int nf = 0; nf < 2; nf++)
#pragma unroll
    for (int ks = 0; ks < 2; ks++)
      bq[nf][ks] = *(const bf16x8*)(qk +
          (rowbase + q0 + wave * 32 + nf * 16 + lm) * 2048 + h * 64 + ks * 32 + quad * 8);

  const int strow = tid >> 3;
  const int js = (tid & 7) ^ ((tid >> 4) & 7);
  const bf16* kstg = qk + (rowbase + strow) * 2048 + 1024 + h * 64 + js * 8;
  const bf16* vstg = vp + ((size_t)hb * 64 + strow) * TSEQ + js * 8;
  const size_t krow32 = (size_t)32 * 2048;
  const size_t vrow32 = (size_t)32 * TSEQ;

  const int sw = (lm >> 1) & 7;

  f32x4 oT[4][2];
#pragma unroll
  for (int mf = 0; mf < 4; mf++)
#pragma unroll
    for (int nf = 0; nf < 2; nf++) oT[mf][nf] = z4;
  float lp[2] = {0.0f, 0.0f};

  const int nkt = 2 * qt + 2;
  const int wrow_lo = q0 + wave * 32;
  const int wrow_hi = wrow_lo + 31;

  for (int kt = 0; kt < nkt; kt++) {
    const int k0 = kt * 64;
    __syncthreads();
    gload_lds16(kstg + (size_t)k0 * 2048, &Ks[tid * 8]);
    gload_lds16(kstg + (size_t)k0 * 2048 + krow32, &Ks[(256 + tid) * 8]);
    gload_lds16(vstg + k0, &Vts[tid * 8]);
    gload_lds16(vstg + k0 + vrow32, &Vts[(256 + tid) * 8]);
    __syncthreads();
    if (k0 > wrow_hi) continue;  // wave fully above diagonal (still barriers)

    // ---- S^T = K Q^T ----
    f32x4 s[4][2];
#pragma unroll
    for (int mf = 0; mf < 4; mf++)
#pragma unroll
      for (int nf = 0; nf < 2; nf++) s[mf][nf] = z4;
#pragma unroll
    for (int ks = 0; ks < 2; ks++) {
      const int kc = ((ks * 4 + quad) ^ sw) * 8;
      bf16x8 ak[4];
#pragma unroll
      for (int mf = 0; mf < 4; mf++)
        ak[mf] = *(const bf16x8*)&Ks[(mf * 16 + lm) * 64 + kc];
#pragma unroll
      for (int mf = 0; mf < 4; mf++)
#pragma unroll
        for (int nf = 0; nf < 2; nf++)
          s[mf][nf] = __builtin_amdgcn_mfma_f32_16x16x32_bf16(ak[mf], bq[nf][ks], s[mf][nf], 0, 0, 0);
    }

    // ---- P = exp2(S^T) (log2e pre-folded); mask only on diagonal tiles ----
    const bool need_mask = (k0 + 63 > wrow_lo);
#pragma unroll
    for (int nf = 0; nf < 2; nf++) {
      const int qrow = q0 + wave * 32 + nf * 16 + lm;
#pragma unroll
      for (int mf = 0; mf < 4; mf++) {
        bf16x4 pk;
        float psum = 0.0f;
#pragma unroll
        for (int rr = 0; rr < 4; rr++) {
          float pv = EXP2F(s[mf][nf][rr]);
          if (need_mask) {
            int kv = k0 + mf * 16 + quad * 4 + rr;
            pv = (kv > qrow) ? 0.0f : pv;
          }
          psum += pv;
          pk[rr] = (bf16)pv;
        }
        lp[nf] += psum;
        *(bf16x4*)&Ps[wave][(nf * 16 + lm) * 64 +
                            (((mf * 2 + (quad >> 1)) ^ sw) * 8 + (quad & 1) * 4)] = pk;
      }
    }

    // ---- O^T += V^T P^T ----
#pragma unroll
    for (int ks = 0; ks < 2; ks++) {
      const int kc = ((ks * 4 + quad) ^ sw) * 8;
      bf16x8 av[4], bp[2];
#pragma unroll
      for (int mf = 0; mf < 4; mf++)
        av[mf] = *(const bf16x8*)&Vts[(mf * 16 + lm) * 64 + kc];
#pragma unroll
      for (int nf = 0; nf < 2; nf++)
        bp[nf] = *(const bf16x8*)&Ps[wave][(nf * 16 + lm) * 64 + kc];
#pragma unroll
      for (int mf = 0; mf < 4; mf++)
#pragma unroll
        for (int nf = 0; nf < 2; nf++)
          oT[mf][nf] = __builtin_amdgcn_mfma_f32_16x16x32_bf16(av[mf], bp[nf], oT[mf][nf], 0, 0, 0);
    }
  }

  float linv[2];
#pragma unroll
  for (int nf = 0; nf < 2; nf++) {
    float l = lp[nf];
    l += __shfl_xor(l, 16, 64);
    l += __shfl_xor(l, 32, 64);
    linv[nf] = 1.0f / l;
  }

#pragma unroll
  for (int nf = 0; nf < 2; nf++) {
    const size_t grow = rowbase + q0 + wave * 32 + nf * 16 + lm;
#pragma unroll
    for (int mf = 0; mf < 4; mf++) {
      bf16x4 ok;
#pragma unroll
      for (int rr = 0; rr < 4; rr++) ok[rr] = (bf16)(oT[mf][nf][rr] * linv[nf]);
      *(bf16x4*)(att + grow * 1024 + h * 64 + mf * 16 + quad * 4) = ok;
    }
  }
}

extern "C" void kernel_launch(void* const* d_in, const int* in_sizes, int n_in,
                              void* d_out, int out_size, void* d_ws, size_t ws_size,
                              hipStream_t stream) {
  const float* x = (const float*)d_in[0];
  const float* w_qkv = (const float*)d_in[1];
  const float* b_qkv = (const float*)d_in[2];
  const float* w_out = (const float*)d_in[3];
  const float* b_out = (const float*)d_in[4];
  float* out = (float*)d_out;

  // Workspace (75.5 MB). ATT aliases Xbf: Xbf is dead once the QKV GEMM has
  // run; flash writes ATT strictly after that on the same stream.
  char* ws = (char*)d_ws;
  bf16* Xbf   = (bf16*)(ws);                 // 8192x1024  (16.78 MB)
  bf16* ATT   = (bf16*)(ws);                 // aliases Xbf
  bf16* Wqkvt = (bf16*)(ws + 16777216);      // 3072x1024  ( 6.29 MB)
  bf16* Woutt = (bf16*)(ws + 23068672);      // 1024x1024  ( 2.10 MB)
  bf16* QK    = (bf16*)(ws + 25165824);      // 8192x2048  (33.55 MB) Q|K
  bf16* VP    = (bf16*)(ws + 58720256);      // [b*1024+h*64+d][t] (16.78 MB)

  prep_kernel<<<8192, 256, 0, stream>>>(x, Xbf, w_qkv, Wqkvt, w_out, Woutt);
  // QKV GEMM: m97 structure, natural raster (see ledger in kernel comment)
  gemm_bf16_kernel<bf16, 128, false><<<dim3(24, 64), 256, 0, stream>>>(
      Xbf, Wqkvt, b_qkv, QK, 8192, 3072, 1024, 2048, QSCALE, 1024, VP);
  flash_attn_kernel<<<dim3(64, 16, 1), 256, 0, stream>>>(QK, VP, ATT);
  // out GEMM: BN 64->128 (2x MFMA:stage ratio, half the A re-fetch, 512
  // blocks = 2 clean rounds at 4 blk/CU) + T1 chunk swizzle (2MB A-chunk +
  // 2MB B both fit per-XCD L2)
  gemm_bf16_kernel<float, 128, true><<<dim3(8, 64), 256, 0, stream>>>(
      ATT, Woutt, b_out, out, 8192, 1024, 1024, 1024, 1.0f, 0, nullptr);
}